// Round 1
// baseline (378.727 us; speedup 1.0000x reference)
//
#include <hip/hip_runtime.h>

#define S_LEN 2048
#define DIM   2048
#define NH    16
#define NKV   4
#define HD    128
#define WIN   512
#define BATCH 2

typedef __bf16 bf16x8 __attribute__((ext_vector_type(8)));
typedef __bf16 bf16x4 __attribute__((ext_vector_type(4)));
typedef float  f32x4  __attribute__((ext_vector_type(4)));

__device__ inline void async_load16(const void* g, void* l) {
  __builtin_amdgcn_global_load_lds(
      (const __attribute__((address_space(1))) unsigned int*)g,
      (__attribute__((address_space(3))) unsigned int*)l, 16, 0, 0);
}

// ---------------- cast fp32 -> bf16 (vectorized x4) ----------------
__global__ __launch_bounds__(256) void cast_bf16_kernel(
    const float* __restrict__ in, __bf16* __restrict__ out, int n4) {
  int i = blockIdx.x * 256 + threadIdx.x;
  if (i < n4) {
    float4 v = ((const float4*)in)[i];
    bf16x4 o;
    o[0] = (__bf16)v.x; o[1] = (__bf16)v.y; o[2] = (__bf16)v.z; o[3] = (__bf16)v.w;
    ((bf16x4*)out)[i] = o;
  }
}

// ---------------- GEMM: C[m][n] = sum_k A[m][k] * Bt[n][k] ----------------
// m97 structure: 128x128 tile, BK=32, global_load_lds(16B), 16x16x32 bf16 MFMA
__global__ __launch_bounds__(256) void gemm_bt(
    const __bf16* __restrict__ A, const __bf16* __restrict__ Bt,
    float* __restrict__ C, int M, int N, int K) {
  __shared__ __bf16 As[128 * 32];
  __shared__ __bf16 Bs[128 * 32];
  const int t = threadIdx.x;
  const int wid = t >> 6, lane = t & 63;
  const int quad = lane >> 4, l15 = lane & 15;
  const long m0 = (long)blockIdx.x * 128, n0 = (long)blockIdx.y * 128;
  const int wm = (wid >> 1) * 64, wn = (wid & 1) * 64;

  const __bf16* ga = A + (m0 + (t >> 2)) * (long)K + (t & 3) * 8;
  const __bf16* gb = Bt + (n0 + (t >> 2)) * (long)K + (t & 3) * 8;
  char* lA = (char*)As + wid * 1024;
  char* lB = (char*)Bs + wid * 1024;
  const long rstride = 64L * K;

  f32x4 zero = {0.f, 0.f, 0.f, 0.f};
  f32x4 acc[4][4];
#pragma unroll
  for (int i = 0; i < 4; ++i)
#pragma unroll
    for (int j = 0; j < 4; ++j) acc[i][j] = zero;

  for (int k0 = 0; k0 < K; k0 += 32) {
    async_load16(ga + k0, lA);
    async_load16(ga + k0 + rstride, lA + 4096);
    async_load16(gb + k0, lB);
    async_load16(gb + k0 + rstride, lB + 4096);
    __syncthreads();  // drains vmcnt for global_load_lds
    bf16x8 af[4], bf[4];
#pragma unroll
    for (int i = 0; i < 4; ++i) {
      af[i] = *(const bf16x8*)(As + (wm + i * 16 + l15) * 32 + quad * 8);
      bf[i] = *(const bf16x8*)(Bs + (wn + i * 16 + l15) * 32 + quad * 8);
    }
#pragma unroll
    for (int i = 0; i < 4; ++i)
#pragma unroll
      for (int j = 0; j < 4; ++j)
        acc[i][j] = __builtin_amdgcn_mfma_f32_16x16x32_bf16(af[i], bf[j], acc[i][j], 0, 0, 0);
    __syncthreads();
  }

#pragma unroll
  for (int i = 0; i < 4; ++i)
#pragma unroll
    for (int j = 0; j < 4; ++j)
#pragma unroll
      for (int r = 0; r < 4; ++r)
        C[(m0 + wm + i * 16 + quad * 4 + r) * (long)N + n0 + wn + j * 16 + l15] = acc[i][j][r];
}

// ---------------- RMSNorm + RoPE + gain (+1/sqrt(HD) folded into q) --------
// one wave per (b,s,head) vector of 128; lane l owns dims l and l+64 (a rope pair)
__global__ __launch_bounds__(256) void normrope_kernel(
    const float* __restrict__ QKV,  // [B*S][3072]  (q:0..2047, k:2048..2559, v:2560..3071)
    const float* __restrict__ gain,
    __bf16* __restrict__ Qo,   // [B][NH][S][HD]
    __bf16* __restrict__ Ko) { // [B][NKV][S][HD]
  const int w = blockIdx.x * 4 + (threadIdx.x >> 6);
  const int lane = threadIdx.x & 63;
  const int NQ = BATCH * S_LEN * NH;  // 65536
  long srcbase;
  __bf16* dst;
  float g;
  int s;
  if (w < NQ) {
    int b = w >> 15, rem = w & 32767;
    s = rem >> 4;
    int h = rem & 15;
    srcbase = ((long)(b * S_LEN + s)) * 3072 + h * HD;
    dst = Qo + ((long)((b * NH + h) * S_LEN + s)) * HD;
    g = gain[h] * 0.08838834764831845f;  // q_gain * 1/sqrt(128)
  } else {
    int w2 = w - NQ;
    int b = w2 >> 13, rem = w2 & 8191;
    s = rem >> 2;
    int kvh = rem & 3;
    srcbase = ((long)(b * S_LEN + s)) * 3072 + 2048 + kvh * HD;
    dst = Ko + ((long)((b * NKV + kvh) * S_LEN + s)) * HD;
    g = 1.f;
  }
  float x0 = QKV[srcbase + lane];
  float x1 = QKV[srcbase + 64 + lane];
  float ss = x0 * x0 + x1 * x1;
#pragma unroll
  for (int off = 1; off < 64; off <<= 1) ss += __shfl_xor(ss, off, 64);
  float rms = rsqrtf(ss * (1.f / 128.f) + 1.1920928955078125e-07f);
  x0 *= rms;
  x1 *= rms;
  float fr = (float)s * powf(10000.f, -(float)lane * (1.f / 64.f));
  float cn, sn;
  sincosf(fr, &sn, &cn);
  float o0 = (x0 * cn + x1 * sn) * g;
  float o1 = (-x0 * sn + x1 * cn) * g;
  dst[lane] = (__bf16)o0;
  dst[lane + 64] = (__bf16)o1;
}

// ---------------- V transpose-cast: QKV v-cols -> Vt[b][kv][d][s] bf16 -----
__global__ __launch_bounds__(256) void vtrans_kernel(
    const float* __restrict__ QKV, __bf16* __restrict__ Vt) {
  __shared__ float tile[32][33];
  const int b = blockIdx.z >> 2, kvh = blockIdx.z & 3;
  const int s0 = blockIdx.x * 32, d0 = blockIdx.y * 32;
  const int tx = threadIdx.x & 31, ty = threadIdx.x >> 5;
#pragma unroll
  for (int r = 0; r < 4; ++r) {
    int s = s0 + ty + r * 8;
    tile[ty + r * 8][tx] = QKV[((long)(b * S_LEN + s)) * 3072 + 2560 + kvh * HD + d0 + tx];
  }
  __syncthreads();
#pragma unroll
  for (int r = 0; r < 4; ++r) {
    int d = d0 + ty + r * 8;
    Vt[((long)((b * NKV + kvh) * HD + d)) * S_LEN + s0 + tx] = (__bf16)tile[tx][ty + r * 8];
  }
}

// ---------------- sliding-window GQA flash attention ----------------
// block = 256 thr = 4 waves; wave w owns q rows [t0+16w, t0+16w+16); TK=32
__global__ __launch_bounds__(256) void attn_kernel(
    const __bf16* __restrict__ Q,   // [B][NH][S][HD]  (pre-scaled by gain/sqrt(HD))
    const __bf16* __restrict__ K,   // [B][NKV][S][HD]
    const __bf16* __restrict__ Vt,  // [B][NKV][HD][S]
    __bf16* __restrict__ Y) {       // [B][S][NH*HD]
  __shared__ __bf16 Ks[32 * 128];   // [key][d]
  __shared__ __bf16 Vs[128 * 32];   // [d][key]  (V^T tile)
  __shared__ __bf16 Ps[4][16 * 32]; // per-wave P: [row][key]

  const int t = threadIdx.x;
  const int wid = t >> 6, lane = t & 63;
  const int quad = lane >> 4, l15 = lane & 15;
  const int qt = blockIdx.x, h = blockIdx.y, b = blockIdx.z;
  const int kv = h >> 2;
  const int t0 = qt * 64;
  const int r0 = t0 + wid * 16;
  const float NEG_INF = -__builtin_inff();

  const __bf16* Qb = Q + ((long)(b * NH + h)) * S_LEN * HD;
  const __bf16* Kb = K + ((long)(b * NKV + kv)) * S_LEN * HD;
  const __bf16* Vb = Vt + ((long)(b * NKV + kv)) * HD * S_LEN;

  // Q fragments (A-layout), 4 k-chunks of 32 over HD
  bf16x8 qf[4];
#pragma unroll
  for (int c = 0; c < 4; ++c)
    qf[c] = *(const bf16x8*)(Qb + (long)(r0 + l15) * HD + c * 32 + quad * 8);

  f32x4 zero = {0.f, 0.f, 0.f, 0.f};
  f32x4 acc[8];
#pragma unroll
  for (int i = 0; i < 8; ++i) acc[i] = zero;
  float m_i[4], l_i[4];
#pragma unroll
  for (int r = 0; r < 4; ++r) { m_i[r] = NEG_INF; l_i[r] = 0.f; }

  int kstart = t0 - (WIN - 1);
  if (kstart < 0) kstart = 0;
  const int ntiles = (t0 + 64 - kstart + 31) / 32;

  const int krow = t >> 4, kcol = (t & 15) * 8;  // K stage: 16 rows/call
  const int vrow = t >> 2, vcol = (t & 3) * 8;   // V stage: 64 rows/call

  for (int it = 0; it < ntiles; ++it) {
    const int kt = kstart + it * 32;
    {
      int gr0 = kt + krow;      if (gr0 > S_LEN - 1) gr0 = S_LEN - 1;
      int gr1 = kt + krow + 16; if (gr1 > S_LEN - 1) gr1 = S_LEN - 1;
      async_load16(Kb + (long)gr0 * HD + kcol, (char*)Ks + wid * 1024);
      async_load16(Kb + (long)gr1 * HD + kcol, (char*)Ks + 4096 + wid * 1024);
      int vc = kt + vcol;       if (vc > S_LEN - 8) vc = S_LEN - 8;
      async_load16(Vb + (long)vrow * S_LEN + vc, (char*)Vs + wid * 1024);
      async_load16(Vb + (long)(vrow + 64) * S_LEN + vc, (char*)Vs + 4096 + wid * 1024);
    }
    __syncthreads();

    // wave-uniform skip of fully-masked tiles (barriers stay outside)
    if (kt <= r0 + 15 && kt + 31 >= r0 - (WIN - 1)) {
      // QK^T: two 16-wide key tiles
      f32x4 sc[2];
      sc[0] = zero; sc[1] = zero;
#pragma unroll
      for (int nt = 0; nt < 2; ++nt)
#pragma unroll
        for (int c = 0; c < 4; ++c) {
          bf16x8 kf = *(const bf16x8*)(Ks + (nt * 16 + l15) * 128 + c * 32 + quad * 8);
          sc[nt] = __builtin_amdgcn_mfma_f32_16x16x32_bf16(qf[c], kf, sc[nt], 0, 0, 0);
        }
      // online softmax (per C/D row = quad*4+r, spread over 16 lanes)
      float p0s[4], p1s[4], alpha[4];
#pragma unroll
      for (int r = 0; r < 4; ++r) {
        const int row = r0 + quad * 4 + r;
        int key0 = kt + l15, key1 = kt + 16 + l15;
        float sv0 = (key0 <= row && key0 >= row - (WIN - 1)) ? sc[0][r] : NEG_INF;
        float sv1 = (key1 <= row && key1 >= row - (WIN - 1)) ? sc[1][r] : NEG_INF;
        float mt = fmaxf(sv0, sv1);
#pragma unroll
        for (int off = 1; off < 16; off <<= 1) mt = fmaxf(mt, __shfl_xor(mt, off, 64));
        float mn = fmaxf(m_i[r], mt);
        alpha[r] = (m_i[r] == NEG_INF) ? 0.f : __expf(m_i[r] - mn);
        float p0 = (sv0 == NEG_INF) ? 0.f : __expf(sv0 - mn);
        float p1 = (sv1 == NEG_INF) ? 0.f : __expf(sv1 - mn);
        float ps = p0 + p1;
#pragma unroll
        for (int off = 1; off < 16; off <<= 1) ps += __shfl_xor(ps, off, 64);
        l_i[r] = alpha[r] * l_i[r] + ps;
        m_i[r] = mn;
        p0s[r] = p0; p1s[r] = p1;
      }
#pragma unroll
      for (int d = 0; d < 8; ++d)
#pragma unroll
        for (int r = 0; r < 4; ++r) acc[d][r] *= alpha[r];
      // P: C-layout -> LDS -> A-layout (per-wave region, no barrier needed)
#pragma unroll
      for (int r = 0; r < 4; ++r) {
        Ps[wid][(quad * 4 + r) * 32 + l15] = (__bf16)p0s[r];
        Ps[wid][(quad * 4 + r) * 32 + 16 + l15] = (__bf16)p1s[r];
      }
      bf16x8 pf = *(const bf16x8*)(&Ps[wid][l15 * 32 + quad * 8]);
#pragma unroll
      for (int d = 0; d < 8; ++d) {
        bf16x8 vf = *(const bf16x8*)(Vs + (d * 16 + l15) * 32 + quad * 8);
        acc[d] = __builtin_amdgcn_mfma_f32_16x16x32_bf16(pf, vf, acc[d], 0, 0, 0);
      }
    }
    __syncthreads();
  }

  // epilogue: y = acc / l, write [b][s][h*128+d] bf16 for the final GEMM
  __bf16* Yb = Y + ((long)b * S_LEN) * DIM + h * HD;
#pragma unroll
  for (int r = 0; r < 4; ++r) {
    float il = 1.f / l_i[r];
#pragma unroll
    for (int d = 0; d < 8; ++d)
      Yb[(long)(r0 + quad * 4 + r) * DIM + d * 16 + l15] = (__bf16)(acc[d][r] * il);
  }
}

// ---------------- launch ----------------
extern "C" void kernel_launch(void* const* d_in, const int* in_sizes, int n_in,
                              void* d_out, int out_size, void* d_ws, size_t ws_size,
                              hipStream_t stream) {
  (void)in_sizes; (void)n_in; (void)out_size; (void)ws_size;
  const float* x  = (const float*)d_in[0];
  const float* Wq = (const float*)d_in[1];
  const float* Wk = (const float*)d_in[2];
  const float* Wv = (const float*)d_in[3];
  const float* Wo = (const float*)d_in[4];
  const float* qg = (const float*)d_in[5];
  float* out = (float*)d_out;

  char* ws = (char*)d_ws;
  size_t off = 0;
  auto alloc = [&](size_t bytes) -> void* {
    void* p = ws + off;
    off += (bytes + 255) & ~(size_t)255;
    return p;
  };
  __bf16* xb   = (__bf16*)alloc(8388608ull * 2);        // x bf16 [4096][2048]; reused as yb
  __bf16* wqkv = (__bf16*)alloc(3072ull * 2048 * 2);    // [Wq;Wk;Wv] bf16 (B^T form)
  __bf16* wob  = (__bf16*)alloc(2048ull * 2048 * 2);    // Wo bf16
  float*  qkv  = (float*)alloc(4096ull * 3072 * 4);     // QKV_raw fp32
  __bf16* qo   = (__bf16*)alloc((size_t)BATCH * NH * S_LEN * HD * 2);
  __bf16* ko   = (__bf16*)alloc((size_t)BATCH * NKV * S_LEN * HD * 2);
  __bf16* vt   = (__bf16*)alloc((size_t)BATCH * NKV * HD * S_LEN * 2);
  __bf16* yb   = xb;  // x no longer needed after QKV GEMM

  cast_bf16_kernel<<<8192, 256, 0, stream>>>(x, xb, 8388608 / 4);
  cast_bf16_kernel<<<4096, 256, 0, stream>>>(Wq, wqkv, 4194304 / 4);
  cast_bf16_kernel<<<1024, 256, 0, stream>>>(Wk, wqkv + 2048ull * 2048, 1048576 / 4);
  cast_bf16_kernel<<<1024, 256, 0, stream>>>(Wv, wqkv + 2560ull * 2048, 1048576 / 4);
  cast_bf16_kernel<<<4096, 256, 0, stream>>>(Wo, wob, 4194304 / 4);

  gemm_bt<<<dim3(32, 24), 256, 0, stream>>>(xb, wqkv, qkv, 4096, 3072, 2048);
  normrope_kernel<<<20480, 256, 0, stream>>>(qkv, qg, qo, ko);
  vtrans_kernel<<<dim3(64, 4, 8), 256, 0, stream>>>(qkv, vt);
  attn_kernel<<<dim3(32, 16, 2), 256, 0, stream>>>(qo, ko, vt, yb);
  gemm_bt<<<dim3(32, 16), 256, 0, stream>>>(yb, wob, out, 4096, 2048, 2048);
}

// Round 2
// 310.481 us; speedup vs baseline: 1.2198x; 1.2198x over previous
//
#include <hip/hip_runtime.h>

#define S_LEN 2048
#define DIM   2048
#define NH    16
#define NKV   4
#define HD    128
#define WIN   512
#define BATCH 2

typedef __bf16 bf16x8 __attribute__((ext_vector_type(8)));
typedef __bf16 bf16x4 __attribute__((ext_vector_type(4)));
typedef float  f32x4  __attribute__((ext_vector_type(4)));

__device__ inline void async_load16(const void* g, void* l) {
  __builtin_amdgcn_global_load_lds(
      (const __attribute__((address_space(1))) unsigned int*)g,
      (__attribute__((address_space(3))) unsigned int*)l, 16, 0, 0);
}

// ---------------- cast fp32 -> bf16: x ----------------
__global__ __launch_bounds__(256) void cast_bf16_kernel(
    const float* __restrict__ in, __bf16* __restrict__ out, int n4) {
  int i = blockIdx.x * 256 + threadIdx.x;
  if (i < n4) {
    float4 v = ((const float4*)in)[i];
    bf16x4 o;
    o[0] = (__bf16)v.x; o[1] = (__bf16)v.y; o[2] = (__bf16)v.z; o[3] = (__bf16)v.w;
    ((bf16x4*)out)[i] = o;
  }
}

// ---------------- fused weight cast: Wq|Wk|Wv -> wqkv, Wo -> wob ----------
__global__ __launch_bounds__(256) void cast_weights_kernel(
    const float* __restrict__ Wq, const float* __restrict__ Wk,
    const float* __restrict__ Wv, const float* __restrict__ Wo,
    __bf16* __restrict__ wqkv, __bf16* __restrict__ wob) {
  int i = blockIdx.x * 256 + threadIdx.x;  // float4 index, total 2621440
  const float* src; __bf16* dst; int off;
  if (i < 1048576)      { src = Wq; dst = wqkv;           off = i; }
  else if (i < 1310720) { src = Wk; dst = wqkv + 4194304; off = i - 1048576; }
  else if (i < 1572864) { src = Wv; dst = wqkv + 5242880; off = i - 1310720; }
  else                  { src = Wo; dst = wob;            off = i - 1572864; }
  float4 v = ((const float4*)src)[off];
  bf16x4 o;
  o[0] = (__bf16)v.x; o[1] = (__bf16)v.y; o[2] = (__bf16)v.z; o[3] = (__bf16)v.w;
  ((bf16x4*)dst)[off] = o;
}

// ---------------- GEMM: C[m][n] = sum_k A[m][k] * Bt[n][k] ----------------
__global__ __launch_bounds__(256) void gemm_bt(
    const __bf16* __restrict__ A, const __bf16* __restrict__ Bt,
    float* __restrict__ C, int M, int N, int K) {
  __shared__ __bf16 As[128 * 32];
  __shared__ __bf16 Bs[128 * 32];
  const int t = threadIdx.x;
  const int wid = t >> 6, lane = t & 63;
  const int quad = lane >> 4, l15 = lane & 15;
  const long m0 = (long)blockIdx.x * 128, n0 = (long)blockIdx.y * 128;
  const int wm = (wid >> 1) * 64, wn = (wid & 1) * 64;

  const __bf16* ga = A + (m0 + (t >> 2)) * (long)K + (t & 3) * 8;
  const __bf16* gb = Bt + (n0 + (t >> 2)) * (long)K + (t & 3) * 8;
  char* lA = (char*)As + wid * 1024;
  char* lB = (char*)Bs + wid * 1024;
  const long rstride = 64L * K;

  f32x4 zero = {0.f, 0.f, 0.f, 0.f};
  f32x4 acc[4][4];
#pragma unroll
  for (int i = 0; i < 4; ++i)
#pragma unroll
    for (int j = 0; j < 4; ++j) acc[i][j] = zero;

  for (int k0 = 0; k0 < K; k0 += 32) {
    async_load16(ga + k0, lA);
    async_load16(ga + k0 + rstride, lA + 4096);
    async_load16(gb + k0, lB);
    async_load16(gb + k0 + rstride, lB + 4096);
    __syncthreads();
    bf16x8 af[4], bf[4];
#pragma unroll
    for (int i = 0; i < 4; ++i) {
      af[i] = *(const bf16x8*)(As + (wm + i * 16 + l15) * 32 + quad * 8);
      bf[i] = *(const bf16x8*)(Bs + (wn + i * 16 + l15) * 32 + quad * 8);
    }
#pragma unroll
    for (int i = 0; i < 4; ++i)
#pragma unroll
      for (int j = 0; j < 4; ++j)
        acc[i][j] = __builtin_amdgcn_mfma_f32_16x16x32_bf16(af[i], bf[j], acc[i][j], 0, 0, 0);
    __syncthreads();
  }

#pragma unroll
  for (int i = 0; i < 4; ++i)
#pragma unroll
    for (int j = 0; j < 4; ++j)
#pragma unroll
      for (int r = 0; r < 4; ++r)
        C[(m0 + wm + i * 16 + quad * 4 + r) * (long)N + n0 + wn + j * 16 + l15] = acc[i][j][r];
}

// ---------------- RMSNorm + RoPE + gain (+1/sqrt(HD) folded into q) --------
__global__ __launch_bounds__(256) void normrope_kernel(
    const float* __restrict__ QKV, const float* __restrict__ gain,
    __bf16* __restrict__ Qo, __bf16* __restrict__ Ko) {
  const int w = blockIdx.x * 4 + (threadIdx.x >> 6);
  const int lane = threadIdx.x & 63;
  const int NQ = BATCH * S_LEN * NH;  // 65536
  long srcbase;
  __bf16* dst;
  float g;
  int s;
  if (w < NQ) {
    int b = w >> 15, rem = w & 32767;
    s = rem >> 4;
    int h = rem & 15;
    srcbase = ((long)(b * S_LEN + s)) * 3072 + h * HD;
    dst = Qo + ((long)((b * NH + h) * S_LEN + s)) * HD;
    g = gain[h] * 0.08838834764831845f;  // q_gain * 1/sqrt(128)
  } else {
    int w2 = w - NQ;
    int b = w2 >> 13, rem = w2 & 8191;
    s = rem >> 2;
    int kvh = rem & 3;
    srcbase = ((long)(b * S_LEN + s)) * 3072 + 2048 + kvh * HD;
    dst = Ko + ((long)((b * NKV + kvh) * S_LEN + s)) * HD;
    g = 1.f;
  }
  float x0 = QKV[srcbase + lane];
  float x1 = QKV[srcbase + 64 + lane];
  float ss = x0 * x0 + x1 * x1;
#pragma unroll
  for (int off = 1; off < 64; off <<= 1) ss += __shfl_xor(ss, off, 64);
  float rms = rsqrtf(ss * (1.f / 128.f) + 1.1920928955078125e-07f);
  x0 *= rms;
  x1 *= rms;
  float fr = (float)s * powf(10000.f, -(float)lane * (1.f / 64.f));
  float cn, sn;
  sincosf(fr, &sn, &cn);
  float o0 = (x0 * cn + x1 * sn) * g;
  float o1 = (-x0 * sn + x1 * cn) * g;
  dst[lane] = (__bf16)o0;
  dst[lane + 64] = (__bf16)o1;
}

// ---------------- V transpose-cast: QKV v-cols -> Vt[b][kv][d][s] bf16 -----
__global__ __launch_bounds__(256) void vtrans_kernel(
    const float* __restrict__ QKV, __bf16* __restrict__ Vt) {
  __shared__ float tile[32][33];
  const int b = blockIdx.z >> 2, kvh = blockIdx.z & 3;
  const int s0 = blockIdx.x * 32, d0 = blockIdx.y * 32;
  const int tx = threadIdx.x & 31, ty = threadIdx.x >> 5;
#pragma unroll
  for (int r = 0; r < 4; ++r) {
    int s = s0 + ty + r * 8;
    tile[ty + r * 8][tx] = QKV[((long)(b * S_LEN + s)) * 3072 + 2560 + kvh * HD + d0 + tx];
  }
  __syncthreads();
#pragma unroll
  for (int r = 0; r < 4; ++r) {
    int d = d0 + ty + r * 8;
    Vt[((long)((b * NKV + kvh) * HD + d)) * S_LEN + s0 + tx] = (__bf16)tile[tx][ty + r * 8];
  }
}

// ---------------- sliding-window GQA attention, fixed-max softmax ----------
// block = 128 thr (2 waves); wave w owns 32 q rows; TK=32 keys/iter.
// Fixed max M = sqrt(128)*|gain| bounds all scores -> p = exp(s-M), no online
// rescale, no in-loop reductions; l accumulated per-lane, reduced in epilogue.
// LDS layouts XOR-swizzled at 16B-chunk granularity (staging picks per-lane
// global addresses; global_load_lds fixes only the LDS side).
__global__ __launch_bounds__(128) void attn_kernel(
    const __bf16* __restrict__ Q,   // [B][NH][S][HD]  (pre-scaled by gain/sqrt(HD))
    const __bf16* __restrict__ K,   // [B][NKV][S][HD]
    const __bf16* __restrict__ Vt,  // [B][NKV][HD][S]
    const float* __restrict__ gain,
    __bf16* __restrict__ Y) {       // [B][S][NH*HD]
  __shared__ __bf16 Ks[32 * 128];   // [key][d], chunk' = chunk ^ (key&7)
  __shared__ __bf16 Vs[128 * 32];   // [d][key], chunk' = chunk ^ ((d>>1)&3)
  __shared__ __bf16 Ps[2][32 * 40]; // per-wave P, padded stride 40

  const int t = threadIdx.x;
  const int wid = t >> 6, lane = t & 63;
  const int quad = lane >> 4, l15 = lane & 15;
  const int qt = 31 - blockIdx.x;  // heavy (large-window) blocks first
  const int h = blockIdx.y, b = blockIdx.z;
  const int kv = h >> 2;
  const int t0 = qt * 64;
  const int r0 = t0 + wid * 32;

  const __bf16* Qb = Q + ((long)(b * NH + h)) * S_LEN * HD;
  const __bf16* Kb = K + ((long)(b * NKV + kv)) * S_LEN * HD;
  const __bf16* Vb = Vt + ((long)(b * NKV + kv)) * HD * S_LEN;
  const float M = 11.3137085f * fabsf(gain[h]);  // sqrt(128)*|g| >= max score

  // Q fragments (A-layout): 2 m-tiles x 4 k-chunks
  bf16x8 qf[2][4];
#pragma unroll
  for (int mt = 0; mt < 2; ++mt)
#pragma unroll
    for (int c = 0; c < 4; ++c)
      qf[mt][c] = *(const bf16x8*)(Qb + (long)(r0 + mt * 16 + l15) * HD + c * 32 + quad * 8);

  f32x4 zero = {0.f, 0.f, 0.f, 0.f};
  f32x4 acc[2][8];
#pragma unroll
  for (int mt = 0; mt < 2; ++mt)
#pragma unroll
    for (int d = 0; d < 8; ++d) acc[mt][d] = zero;
  float lac[2][4];
#pragma unroll
  for (int mt = 0; mt < 2; ++mt)
#pragma unroll
    for (int r = 0; r < 4; ++r) lac[mt][r] = 0.f;

  // staging offsets (this wave's 4 calls each for K and V)
  int koff[4], voff[4];
#pragma unroll
  for (int jj = 0; jj < 4; ++jj) {
    int j = wid * 4 + jj;
    int kr = j * 4 + (lane >> 4);
    koff[jj] = kr * HD + (((lane & 15) ^ (kr & 7)) << 3);
    int vr = j * 16 + (lane >> 2);
    voff[jj] = vr * S_LEN + (((lane & 3) ^ ((vr >> 1) & 3)) << 3);
  }

  const int kstart = (t0 >= WIN) ? (t0 - WIN) : 0;
  const int ntiles = (t0 + 64 - kstart) >> 5;

  for (int it = 0; it < ntiles; ++it) {
    const int kt = kstart + it * 32;
#pragma unroll
    for (int jj = 0; jj < 4; ++jj) {
      int j = wid * 4 + jj;
      async_load16(Kb + (long)kt * HD + koff[jj], (char*)Ks + j * 1024);
      async_load16(Vb + kt + voff[jj], (char*)Vs + j * 1024);
    }
    __syncthreads();

    if (kt <= r0 + 31 && kt + 31 >= r0 - (WIN - 1)) {
      // QK^T: 2 key-col tiles x 4 k-chunks; kf shared by both m-tiles
      f32x4 sc[2][2];
      sc[0][0] = zero; sc[0][1] = zero; sc[1][0] = zero; sc[1][1] = zero;
#pragma unroll
      for (int nt = 0; nt < 2; ++nt)
#pragma unroll
        for (int c = 0; c < 4; ++c) {
          bf16x8 kf = *(const bf16x8*)(Ks + (nt * 16 + l15) * HD +
                                       (((c * 4 + quad) ^ (l15 & 7)) << 3));
          sc[0][nt] = __builtin_amdgcn_mfma_f32_16x16x32_bf16(qf[0][c], kf, sc[0][nt], 0, 0, 0);
          sc[1][nt] = __builtin_amdgcn_mfma_f32_16x16x32_bf16(qf[1][c], kf, sc[1][nt], 0, 0, 0);
        }
      // fixed-max softmax: mask + exp, accumulate l per-lane, stash P
#pragma unroll
      for (int mt = 0; mt < 2; ++mt)
#pragma unroll
        for (int r = 0; r < 4; ++r) {
          const int row = r0 + mt * 16 + quad * 4 + r;
#pragma unroll
          for (int nt = 0; nt < 2; ++nt) {
            const int key = kt + nt * 16 + l15;
            float p = (key <= row && key >= row - (WIN - 1))
                          ? __expf(sc[mt][nt][r] - M) : 0.f;
            lac[mt][r] += p;
            Ps[wid][(mt * 16 + quad * 4 + r) * 40 + nt * 16 + l15] = (__bf16)p;
          }
        }
      // P (A-layout) and PV
      bf16x8 pf[2];
#pragma unroll
      for (int mt = 0; mt < 2; ++mt)
        pf[mt] = *(const bf16x8*)(&Ps[wid][(mt * 16 + l15) * 40 + quad * 8]);
#pragma unroll
      for (int d = 0; d < 8; ++d) {
        bf16x8 vf = *(const bf16x8*)(Vs + (d * 16 + l15) * 32 +
                                     ((quad ^ ((l15 >> 1) & 3)) << 3));
        acc[0][d] = __builtin_amdgcn_mfma_f32_16x16x32_bf16(pf[0], vf, acc[0][d], 0, 0, 0);
        acc[1][d] = __builtin_amdgcn_mfma_f32_16x16x32_bf16(pf[1], vf, acc[1][d], 0, 0, 0);
      }
    }
    __syncthreads();
  }

  // epilogue: reduce l across the 16 col-lanes, normalize, store
  __bf16* Yb = Y + ((long)b * S_LEN) * DIM + h * HD;
#pragma unroll
  for (int mt = 0; mt < 2; ++mt)
#pragma unroll
    for (int r = 0; r < 4; ++r) {
      float ls = lac[mt][r];
#pragma unroll
      for (int off = 1; off < 16; off <<= 1) ls += __shfl_xor(ls, off, 64);
      float il = 1.f / ls;
#pragma unroll
      for (int d = 0; d < 8; ++d)
        Yb[(long)(r0 + mt * 16 + quad * 4 + r) * DIM + d * 16 + l15] =
            (__bf16)(acc[mt][d][r] * il);
    }
}

// ---------------- launch ----------------
extern "C" void kernel_launch(void* const* d_in, const int* in_sizes, int n_in,
                              void* d_out, int out_size, void* d_ws, size_t ws_size,
                              hipStream_t stream) {
  (void)in_sizes; (void)n_in; (void)out_size; (void)ws_size;
  const float* x  = (const float*)d_in[0];
  const float* Wq = (const float*)d_in[1];
  const float* Wk = (const float*)d_in[2];
  const float* Wv = (const float*)d_in[3];
  const float* Wo = (const float*)d_in[4];
  const float* qg = (const float*)d_in[5];
  float* out = (float*)d_out;

  char* ws = (char*)d_ws;
  size_t off = 0;
  auto alloc = [&](size_t bytes) -> void* {
    void* p = ws + off;
    off += (bytes + 255) & ~(size_t)255;
    return p;
  };
  __bf16* xb   = (__bf16*)alloc(8388608ull * 2);        // x bf16; reused as yb
  __bf16* wqkv = (__bf16*)alloc(3072ull * 2048 * 2);    // [Wq;Wk;Wv] bf16 (B^T)
  __bf16* wob  = (__bf16*)alloc(2048ull * 2048 * 2);    // Wo bf16
  float*  qkv  = (float*)alloc(4096ull * 3072 * 4);     // QKV_raw fp32
  __bf16* qo   = (__bf16*)alloc((size_t)BATCH * NH * S_LEN * HD * 2);
  __bf16* ko   = (__bf16*)alloc((size_t)BATCH * NKV * S_LEN * HD * 2);
  __bf16* vt   = (__bf16*)alloc((size_t)BATCH * NKV * HD * S_LEN * 2);
  __bf16* yb   = xb;

  cast_bf16_kernel<<<8192, 256, 0, stream>>>(x, xb, 8388608 / 4);
  cast_weights_kernel<<<10240, 256, 0, stream>>>(Wq, Wk, Wv, Wo, wqkv, wob);

  gemm_bt<<<dim3(32, 24), 256, 0, stream>>>(xb, wqkv, qkv, 4096, 3072, 2048);
  normrope_kernel<<<20480, 256, 0, stream>>>(qkv, qg, qo, ko);
  vtrans_kernel<<<dim3(64, 4, 8), 256, 0, stream>>>(qkv, vt);
  attn_kernel<<<dim3(32, 16, 2), 128, 0, stream>>>(qo, ko, vt, qg, yb);
  gemm_bt<<<dim3(32, 16), 256, 0, stream>>>(yb, wob, out, 4096, 2048, 2048);
}

// Round 3
// 283.932 us; speedup vs baseline: 1.3339x; 1.0935x over previous
//
#include <hip/hip_runtime.h>

#define S_LEN 2048
#define DIM   2048
#define NH    16
#define NKV   4
#define HD    128
#define WIN   512
#define BATCH 2

typedef __bf16 bf16x8 __attribute__((ext_vector_type(8)));
typedef __bf16 bf16x4 __attribute__((ext_vector_type(4)));
typedef float  f32x4  __attribute__((ext_vector_type(4)));

__device__ inline void async_load16(const void* g, void* l) {
  __builtin_amdgcn_global_load_lds(
      (const __attribute__((address_space(1))) unsigned int*)g,
      (__attribute__((address_space(3))) unsigned int*)l, 16, 0, 0);
}

// ---------------- RoPE tables: cos/sin [2048][64] fp32 ----------------
__global__ __launch_bounds__(256) void rope_tables_kernel(
    float* __restrict__ cosT, float* __restrict__ sinT) {
  int idx = blockIdx.x * 256 + threadIdx.x;  // 131072 total
  int s = idx >> 6, d = idx & 63;
  float f = (float)s * powf(10000.f, -(float)d * (1.f / 64.f));
  float sn, cs;
  sincosf(f, &sn, &cs);
  cosT[idx] = cs;
  sinT[idx] = sn;
}

// ---------------- cast fp32 -> bf16: x ----------------
__global__ __launch_bounds__(256) void cast_bf16_kernel(
    const float* __restrict__ in, __bf16* __restrict__ out, int n4) {
  int i = blockIdx.x * 256 + threadIdx.x;
  if (i < n4) {
    float4 v = ((const float4*)in)[i];
    bf16x4 o;
    o[0] = (__bf16)v.x; o[1] = (__bf16)v.y; o[2] = (__bf16)v.z; o[3] = (__bf16)v.w;
    ((bf16x4*)out)[i] = o;
  }
}

// ------- weight cast + RoPE-pair column permutation for q/k heads -------
// perm: new col n holds old dim rmp(n) = (n>>5)*16 + (n&15) + 64*((n>>4)&1)
// so pair (d, d+64) lands in j-tiles (2a, 2a+1) of the same lane in C-layout.
__global__ __launch_bounds__(256) void cast_weights_kernel(
    const float* __restrict__ Wq, const float* __restrict__ Wk,
    const float* __restrict__ Wv, const float* __restrict__ Wo,
    __bf16* __restrict__ wqkv, __bf16* __restrict__ wob) {
  int i = blockIdx.x * 256 + threadIdx.x;  // float4 idx over 5120 rows x 512
  int orow = i >> 9, c = i & 511;
  const float* src;
  __bf16* dst;
  long soff;
  if (orow < 2048) {
    int n = orow & 127;
    int sr = (orow & ~127) + ((n >> 5) << 4) + (n & 15) + (((n >> 4) & 1) << 6);
    src = Wq; soff = (long)sr * 512 + c; dst = wqkv + (long)orow * 2048;
  } else if (orow < 2560) {
    int lr = orow - 2048, n = lr & 127;
    int sr = (lr & ~127) + ((n >> 5) << 4) + (n & 15) + (((n >> 4) & 1) << 6);
    src = Wk; soff = (long)sr * 512 + c; dst = wqkv + (long)orow * 2048;
  } else if (orow < 3072) {
    src = Wv; soff = (long)(orow - 2560) * 512 + c; dst = wqkv + (long)orow * 2048;
  } else {
    src = Wo; soff = (long)(orow - 3072) * 512 + c; dst = wob + (long)(orow - 3072) * 2048;
  }
  float4 v = ((const float4*)src)[soff];
  bf16x4 o;
  o[0] = (__bf16)v.x; o[1] = (__bf16)v.y; o[2] = (__bf16)v.z; o[3] = (__bf16)v.w;
  ((bf16x4*)(dst))[c] = o;
}

// ---------------- plain GEMM (O-projection): C = A * Bt^T ----------------
__global__ __launch_bounds__(256) void gemm_bt(
    const __bf16* __restrict__ A, const __bf16* __restrict__ Bt,
    float* __restrict__ C, int M, int N, int K) {
  __shared__ __bf16 As[128 * 32];
  __shared__ __bf16 Bs[128 * 32];
  const int t = threadIdx.x;
  const int wid = t >> 6, lane = t & 63;
  const int quad = lane >> 4, l15 = lane & 15;
  const long m0 = (long)blockIdx.x * 128, n0 = (long)blockIdx.y * 128;
  const int wm = (wid >> 1) * 64, wn = (wid & 1) * 64;

  const __bf16* ga = A + (m0 + (t >> 2)) * (long)K + (t & 3) * 8;
  const __bf16* gb = Bt + (n0 + (t >> 2)) * (long)K + (t & 3) * 8;
  char* lA = (char*)As + wid * 1024;
  char* lB = (char*)Bs + wid * 1024;
  const long rstride = 64L * K;

  f32x4 zero = {0.f, 0.f, 0.f, 0.f};
  f32x4 acc[4][4];
#pragma unroll
  for (int i = 0; i < 4; ++i)
#pragma unroll
    for (int j = 0; j < 4; ++j) acc[i][j] = zero;

  for (int k0 = 0; k0 < K; k0 += 32) {
    async_load16(ga + k0, lA);
    async_load16(ga + k0 + rstride, lA + 4096);
    async_load16(gb + k0, lB);
    async_load16(gb + k0 + rstride, lB + 4096);
    __syncthreads();
    bf16x8 af[4], bfr[4];
#pragma unroll
    for (int i = 0; i < 4; ++i) {
      af[i] = *(const bf16x8*)(As + (wm + i * 16 + l15) * 32 + quad * 8);
      bfr[i] = *(const bf16x8*)(Bs + (wn + i * 16 + l15) * 32 + quad * 8);
    }
#pragma unroll
    for (int i = 0; i < 4; ++i)
#pragma unroll
      for (int j = 0; j < 4; ++j)
        acc[i][j] = __builtin_amdgcn_mfma_f32_16x16x32_bf16(af[i], bfr[j], acc[i][j], 0, 0, 0);
    __syncthreads();
  }

#pragma unroll
  for (int i = 0; i < 4; ++i)
#pragma unroll
    for (int j = 0; j < 4; ++j)
#pragma unroll
      for (int r = 0; r < 4; ++r)
        C[(m0 + wm + i * 16 + quad * 4 + r) * (long)N + n0 + wn + j * 16 + l15] = acc[i][j][r];
}

// -------- QKV GEMM with fused RMSNorm + RoPE + gain + V-transpose --------
// N=3072: blockIdx.y<16 -> q head, 16..19 -> k head, 20..23 -> v head.
__global__ __launch_bounds__(256) void gemm_qkv(
    const __bf16* __restrict__ A,    // x bf16 [4096][2048]
    const __bf16* __restrict__ Bt,   // wqkv [3072][2048] (q/k rows permuted)
    const float* __restrict__ gain,
    const float* __restrict__ cosT, const float* __restrict__ sinT,
    __bf16* __restrict__ Qo,   // [B][NH][S][HD] (permuted d)
    __bf16* __restrict__ Ko,   // [B][NKV][S][HD] (permuted d)
    __bf16* __restrict__ Vt) { // [B][NKV][HD][S] (true d)
  __shared__ __bf16 As[128 * 32];
  __shared__ __bf16 Bs[128 * 32];
  const int K = 2048;
  const int t = threadIdx.x;
  const int wid = t >> 6, lane = t & 63;
  const int quad = lane >> 4, l15 = lane & 15;
  const long m0 = (long)blockIdx.x * 128, n0 = (long)blockIdx.y * 128;
  const int wm = (wid >> 1) * 64, wn = (wid & 1) * 64;

  const __bf16* ga = A + (m0 + (t >> 2)) * (long)K + (t & 3) * 8;
  const __bf16* gb = Bt + (n0 + (t >> 2)) * (long)K + (t & 3) * 8;
  char* lA = (char*)As + wid * 1024;
  char* lB = (char*)Bs + wid * 1024;
  const long rstride = 64L * K;

  f32x4 zero = {0.f, 0.f, 0.f, 0.f};
  f32x4 acc[4][4];
#pragma unroll
  for (int i = 0; i < 4; ++i)
#pragma unroll
    for (int j = 0; j < 4; ++j) acc[i][j] = zero;

  for (int k0 = 0; k0 < K; k0 += 32) {
    async_load16(ga + k0, lA);
    async_load16(ga + k0 + rstride, lA + 4096);
    async_load16(gb + k0, lB);
    async_load16(gb + k0 + rstride, lB + 4096);
    __syncthreads();
    bf16x8 af[4], bfr[4];
#pragma unroll
    for (int i = 0; i < 4; ++i) {
      af[i] = *(const bf16x8*)(As + (wm + i * 16 + l15) * 32 + quad * 8);
      bfr[i] = *(const bf16x8*)(Bs + (wn + i * 16 + l15) * 32 + quad * 8);
    }
#pragma unroll
    for (int i = 0; i < 4; ++i)
#pragma unroll
      for (int j = 0; j < 4; ++j)
        acc[i][j] = __builtin_amdgcn_mfma_f32_16x16x32_bf16(af[i], bfr[j], acc[i][j], 0, 0, 0);
    __syncthreads();
  }

  const int by = blockIdx.y;
  const int srow0 = (int)(m0 & 2047);  // s of tile row 0 (block is within one b)
  const int bb = (int)(m0 >> 11);

  if (by >= 20) {
    // ---- V: cast + transpose to Vt[b][kv][d][s] ----
    const int kvh = by - 20;
    __bf16* Vb = Vt + ((long)(bb * NKV + kvh)) * HD * S_LEN;
#pragma unroll
    for (int i = 0; i < 4; ++i)
#pragma unroll
      for (int j = 0; j < 4; ++j) {
        int d = wn + j * 16 + l15;
        int s0 = srow0 + wm + i * 16 + quad * 4;
        bf16x4 o;
#pragma unroll
        for (int r = 0; r < 4; ++r) o[r] = (__bf16)acc[i][j][r];
        *(bf16x4*)(Vb + (long)d * S_LEN + s0) = o;
      }
  } else {
    // ---- Q/K: RMSNorm (cross-wave via LDS) + RoPE + gain + store ----
    float* sums = (float*)As;  // [128][2] partial row sums of squares
#pragma unroll
    for (int i = 0; i < 4; ++i)
#pragma unroll
      for (int r = 0; r < 4; ++r) {
        float t2 = acc[i][0][r] * acc[i][0][r] + acc[i][1][r] * acc[i][1][r] +
                   acc[i][2][r] * acc[i][2][r] + acc[i][3][r] * acc[i][3][r];
#pragma unroll
        for (int off = 1; off < 16; off <<= 1) t2 += __shfl_xor(t2, off, 64);
        if (l15 == 0) sums[(wm + i * 16 + quad * 4 + r) * 2 + (wn >> 6)] = t2;
      }
    __syncthreads();

    float g;
    __bf16* base;
    if (by < 16) {
      g = gain[by] * 0.08838834764831845f;  // q_gain / sqrt(HD)
      base = Qo + ((long)(bb * NH + by)) * S_LEN * HD;
    } else {
      g = 1.f;
      base = Ko + ((long)(bb * NKV + (by - 16))) * S_LEN * HD;
    }
#pragma unroll
    for (int i = 0; i < 4; ++i)
#pragma unroll
      for (int r = 0; r < 4; ++r) {
        int lrow = wm + i * 16 + quad * 4 + r;
        int srow = srow0 + lrow;
        float rs = rsqrtf((sums[lrow * 2] + sums[lrow * 2 + 1]) * (1.f / 128.f) +
                          1.1920928955078125e-07f);
#pragma unroll
        for (int a = 0; a < 2; ++a) {
          int dlow = (wn >> 1) + a * 16 + l15;
          float cv = cosT[srow * 64 + dlow];
          float sv = sinT[srow * 64 + dlow];
          float x1 = acc[i][2 * a][r] * rs;
          float x2 = acc[i][2 * a + 1][r] * rs;
          base[(long)srow * HD + wn + (2 * a) * 16 + l15] = (__bf16)((x1 * cv + x2 * sv) * g);
          base[(long)srow * HD + wn + (2 * a + 1) * 16 + l15] = (__bf16)((-x1 * sv + x2 * cv) * g);
        }
      }
  }
}

// ---------------- sliding-window GQA attention, fixed-max softmax ----------
// 2 waves x 32 q-rows; TK=64 keys/iter; all LDS XOR-swizzled (16B granule).
__global__ __launch_bounds__(128) void attn_kernel(
    const __bf16* __restrict__ Q,   // [B][NH][S][HD] (perm d, pre-scaled)
    const __bf16* __restrict__ K,   // [B][NKV][S][HD] (perm d)
    const __bf16* __restrict__ Vt,  // [B][NKV][HD][S] (true d)
    const float* __restrict__ gain,
    __bf16* __restrict__ Y) {       // [B][S][NH*HD]
  __shared__ __bf16 Ks[64 * 128];   // [key][d], chunk' = chunk ^ (key&7)
  __shared__ __bf16 Vs[128 * 64];   // [d][key], chunk' = chunk ^ (d&7)
  __shared__ __bf16 Ps[2][32 * 64]; // per-wave P, chunk' = chunk ^ (row&7)

  const int t = threadIdx.x;
  const int wid = t >> 6, lane = t & 63;
  const int quad = lane >> 4, l15 = lane & 15;
  const int qt = 31 - blockIdx.x;  // heavy blocks first
  const int h = blockIdx.y, b = blockIdx.z;
  const int kv = h >> 2;
  const int t0 = qt * 64;
  const int r0 = t0 + wid * 32;

  const __bf16* Qb = Q + ((long)(b * NH + h)) * S_LEN * HD;
  const __bf16* Kb = K + ((long)(b * NKV + kv)) * S_LEN * HD;
  const __bf16* Vb = Vt + ((long)(b * NKV + kv)) * HD * S_LEN;
  const float M = 11.3137085f * fabsf(gain[h]);  // bound on all scores

  bf16x8 qf[2][4];
#pragma unroll
  for (int mt = 0; mt < 2; ++mt)
#pragma unroll
    for (int c = 0; c < 4; ++c)
      qf[mt][c] = *(const bf16x8*)(Qb + (long)(r0 + mt * 16 + l15) * HD + c * 32 + quad * 8);

  f32x4 zero = {0.f, 0.f, 0.f, 0.f};
  f32x4 acc[2][8];
#pragma unroll
  for (int mt = 0; mt < 2; ++mt)
#pragma unroll
    for (int d = 0; d < 8; ++d) acc[mt][d] = zero;
  float lac[2][4];
#pragma unroll
  for (int mt = 0; mt < 2; ++mt)
#pragma unroll
    for (int r = 0; r < 4; ++r) lac[mt][r] = 0.f;

  // staging: 8 K-rounds + 8 V-rounds per wave, 1 KB each
  int koff[8], voff[8];
#pragma unroll
  for (int jj = 0; jj < 8; ++jj) {
    int kr = wid * 32 + jj * 4 + (lane >> 4);
    koff[jj] = kr * HD + (((lane & 15) ^ (kr & 7)) << 3);
    int vr = wid * 64 + jj * 8 + (lane >> 3);
    voff[jj] = vr * S_LEN + (((lane & 7) ^ (vr & 7)) << 3);
  }

  const int kstart = (t0 >= WIN) ? (t0 - WIN) : 0;
  const int ntiles = (t0 + 64 - kstart) >> 6;

  for (int it = 0; it < ntiles; ++it) {
    const int kt = kstart + it * 64;
#pragma unroll
    for (int jj = 0; jj < 8; ++jj) {
      async_load16(Kb + (long)kt * HD + koff[jj], (char*)Ks + wid * 8192 + jj * 1024);
      async_load16(Vb + kt + voff[jj], (char*)Vs + wid * 8192 + jj * 1024);
    }
    __syncthreads();

    if (kt <= r0 + 31 && kt + 63 >= r0 - (WIN - 1)) {
      f32x4 sc[2][4];
#pragma unroll
      for (int nt = 0; nt < 4; ++nt) { sc[0][nt] = zero; sc[1][nt] = zero; }
#pragma unroll
      for (int nt = 0; nt < 4; ++nt)
#pragma unroll
        for (int c = 0; c < 4; ++c) {
          bf16x8 kf = *(const bf16x8*)(Ks + (nt * 16 + l15) * 128 +
                                       (((c * 4 + quad) ^ (l15 & 7)) << 3));
          sc[0][nt] = __builtin_amdgcn_mfma_f32_16x16x32_bf16(qf[0][c], kf, sc[0][nt], 0, 0, 0);
          sc[1][nt] = __builtin_amdgcn_mfma_f32_16x16x32_bf16(qf[1][c], kf, sc[1][nt], 0, 0, 0);
        }
#pragma unroll
      for (int mt = 0; mt < 2; ++mt)
#pragma unroll
        for (int r = 0; r < 4; ++r) {
          const int prow = mt * 16 + quad * 4 + r;
          const int row = r0 + prow;
#pragma unroll
          for (int nt = 0; nt < 4; ++nt) {
            const int key = kt + nt * 16 + l15;
            float p = (key <= row && key >= row - (WIN - 1))
                          ? __expf(sc[mt][nt][r] - M) : 0.f;
            lac[mt][r] += p;
            int chunk = nt * 2 + (l15 >> 3);
            Ps[wid][prow * 64 + ((chunk ^ (prow & 7)) << 3) + (l15 & 7)] = (__bf16)p;
          }
        }
      bf16x8 pf[2][2];
#pragma unroll
      for (int mt = 0; mt < 2; ++mt)
#pragma unroll
        for (int kc = 0; kc < 2; ++kc)
          pf[mt][kc] = *(const bf16x8*)(&Ps[wid][(mt * 16 + l15) * 64 +
                                                 (((kc * 4 + quad) ^ (l15 & 7)) << 3)]);
#pragma unroll
      for (int dt = 0; dt < 8; ++dt)
#pragma unroll
        for (int kc = 0; kc < 2; ++kc) {
          bf16x8 vf = *(const bf16x8*)(Vs + (dt * 16 + l15) * 64 +
                                       (((kc * 4 + quad) ^ (l15 & 7)) << 3));
          acc[0][dt] = __builtin_amdgcn_mfma_f32_16x16x32_bf16(pf[0][kc], vf, acc[0][dt], 0, 0, 0);
          acc[1][dt] = __builtin_amdgcn_mfma_f32_16x16x32_bf16(pf[1][kc], vf, acc[1][dt], 0, 0, 0);
        }
    }
    __syncthreads();
  }

  __bf16* Yb = Y + ((long)b * S_LEN) * DIM + h * HD;
#pragma unroll
  for (int mt = 0; mt < 2; ++mt)
#pragma unroll
    for (int r = 0; r < 4; ++r) {
      float ls = lac[mt][r];
#pragma unroll
      for (int off = 1; off < 16; off <<= 1) ls += __shfl_xor(ls, off, 64);
      float il = 1.f / ls;
#pragma unroll
      for (int d = 0; d < 8; ++d)
        Yb[(long)(r0 + mt * 16 + quad * 4 + r) * DIM + d * 16 + l15] =
            (__bf16)(acc[mt][d][r] * il);
    }
}

// ---------------- launch ----------------
extern "C" void kernel_launch(void* const* d_in, const int* in_sizes, int n_in,
                              void* d_out, int out_size, void* d_ws, size_t ws_size,
                              hipStream_t stream) {
  (void)in_sizes; (void)n_in; (void)out_size; (void)ws_size;
  const float* x  = (const float*)d_in[0];
  const float* Wq = (const float*)d_in[1];
  const float* Wk = (const float*)d_in[2];
  const float* Wv = (const float*)d_in[3];
  const float* Wo = (const float*)d_in[4];
  const float* qg = (const float*)d_in[5];
  float* out = (float*)d_out;

  char* ws = (char*)d_ws;
  size_t off = 0;
  auto alloc = [&](size_t bytes) -> void* {
    void* p = ws + off;
    off += (bytes + 255) & ~(size_t)255;
    return p;
  };
  __bf16* xb   = (__bf16*)alloc(8388608ull * 2);      // x bf16; reused as yb
  __bf16* wqkv = (__bf16*)alloc(3072ull * 2048 * 2);  // permuted q/k weight rows
  __bf16* wob  = (__bf16*)alloc(2048ull * 2048 * 2);
  __bf16* qo   = (__bf16*)alloc((size_t)BATCH * NH * S_LEN * HD * 2);
  __bf16* ko   = (__bf16*)alloc((size_t)BATCH * NKV * S_LEN * HD * 2);
  __bf16* vt   = (__bf16*)alloc((size_t)BATCH * NKV * HD * S_LEN * 2);
  float*  cosT = (float*)alloc(2048ull * 64 * 4);
  float*  sinT = (float*)alloc(2048ull * 64 * 4);
  __bf16* yb   = xb;

  rope_tables_kernel<<<512, 256, 0, stream>>>(cosT, sinT);
  cast_bf16_kernel<<<8192, 256, 0, stream>>>(x, xb, 8388608 / 4);
  cast_weights_kernel<<<10240, 256, 0, stream>>>(Wq, Wk, Wv, Wo, wqkv, wob);

  gemm_qkv<<<dim3(32, 24), 256, 0, stream>>>(xb, wqkv, qg, cosT, sinT, qo, ko, vt);
  attn_kernel<<<dim3(32, 16, 2), 128, 0, stream>>>(qo, ko, vt, qg, yb);
  gemm_bt<<<dim3(32, 16), 256, 0, stream>>>(yb, wob, out, 4096, 2048, 2048);
}